// Round 6
// baseline (382.874 us; speedup 1.0000x reference)
//
#include <hip/hip_runtime.h>

#define T_DIM 8192
#define N_DIM 8
#define C_DIM 64
#define KB    2048
#define NT    (N_DIM * T_DIM)        // 65536 rows
#define TOTX  ((size_t)NT * C_DIM)   // 4194304 elements
#define NBLK  (NT / 64)              // 1024 blocks
#define LISTCAP 4096
#define TAU   2e-3f

// Scratch lives inside out's x_d region (out + NT), which xd_kernel
// overwrites LAST. Offsets in floats from out+NT:
#define SCR_COUNT 0      // int
#define SCR_LIST  16     // int[LISTCAP]
#define SCR_PART  8192   // float[NBLK][8]

// numpy pairwise sum (n=64, contiguous) of squares: products rounded f32,
// 8-accumulator loop, combine ((r0+r1)+(r2+r3))+((r4+r5)+(r6+r7)).
__device__ __forceinline__ float np_sumsq64(const float* __restrict__ a) {
    float r[8];
    #pragma unroll
    for (int j = 0; j < 8; ++j) r[j] = __fmul_rn(a[j], a[j]);
    #pragma unroll
    for (int i = 8; i < 64; i += 8)
        #pragma unroll
        for (int j = 0; j < 8; ++j)
            r[j] = __fadd_rn(r[j], __fmul_rn(a[i + j], a[i + j]));
    return __fadd_rn(__fadd_rn(__fadd_rn(r[0], r[1]), __fadd_rn(r[2], r[3])),
                     __fadd_rn(__fadd_rn(r[4], r[5]), __fadd_rn(r[6], r[7])));
}

__global__ void init_kernel(float* out) {
    if (threadIdx.x == 0) ((int*)(out + NT))[SCR_COUNT] = 0;
}

// ------------------------------------------------------------------ argmin ----
// Block: 256 threads, 64 rows. K tiled in 128-bin chunks staged in LDS.
// dot accumulation: sequential ascending-c fmaf (bit-matches BLAS sgemm).
__global__ __launch_bounds__(256) void argmin_kernel(const float* __restrict__ x,
                                                     const float* __restrict__ mask,
                                                     const float* __restrict__ k,
                                                     float* __restrict__ out) {
    __shared__ float xs[C_DIM][68];
    __shared__ float ks[128][68];
    __shared__ float kns[128];
    __shared__ int   sbest[64];
    __shared__ float sbestv[64];
    __shared__ float sacc[4][8];

    int*   count    = (int*)(out + NT) + SCR_COUNT;
    int*   flaglist = (int*)(out + NT) + SCR_LIST;
    float* partials = (out + NT) + SCR_PART;

    const int tid = threadIdx.x;
    const int r0  = blockIdx.x * 64;
    const int n   = r0 / T_DIM;
    const int t0  = r0 % T_DIM;

    #pragma unroll
    for (int it = 0; it < 4; ++it) {
        int idx = it * 256 + tid;
        int c   = idx >> 4;
        int q   = idx & 15;
        float4 v = *(const float4*)(x + ((size_t)n * C_DIM + c) * T_DIM + t0 + q * 4);
        *(float4*)&xs[c][q * 4] = v;
    }

    const int tb = tid & 15;
    const int tr = tid >> 4;

    float bestv[4], best2v[4];
    int   bestb[4];
    #pragma unroll
    for (int i = 0; i < 4; ++i) {
        bestv[i] = __builtin_inff(); best2v[i] = __builtin_inff(); bestb[i] = 0x7fffffff;
    }

    for (int tile = 0; tile < KB / 128; ++tile) {
        const int b0 = tile * 128;
        __syncthreads();
        #pragma unroll
        for (int it = 0; it < 8; ++it) {
            int idx = it * 256 + tid;
            int bb  = idx >> 4;
            int c4  = idx & 15;
            int ph  = c4 ^ (bb >> 3);
            float4 v = *(const float4*)(k + (size_t)(b0 + bb) * C_DIM + c4 * 4);
            *(float4*)&ks[bb][ph * 4] = v;
            float kn = v.x * v.x;
            kn = fmaf(v.y, v.y, kn);
            kn = fmaf(v.z, v.z, kn);
            kn = fmaf(v.w, v.w, kn);
            kn += __shfl_xor(kn, 1, 64);
            kn += __shfl_xor(kn, 2, 64);
            kn += __shfl_xor(kn, 4, 64);
            kn += __shfl_xor(kn, 8, 64);
            if (c4 == 0) kns[bb] = kn;
        }
        __syncthreads();

        float dot[4][8];
        #pragma unroll
        for (int i = 0; i < 4; ++i)
            #pragma unroll
            for (int j = 0; j < 8; ++j) dot[i][j] = 0.f;

        #pragma unroll 4
        for (int c4 = 0; c4 < 16; ++c4) {
            float4 xr[4];
            #pragma unroll
            for (int i = 0; i < 4; ++i)
                xr[i] = *(const float4*)&xs[c4 * 4 + i][tr * 4];
            #pragma unroll
            for (int j = 0; j < 8; ++j) {
                const int bb = tb * 8 + j;
                float4 kv = *(const float4*)&ks[bb][((c4 ^ tb) & 15) * 4];
                dot[0][j] = fmaf(xr[0].x, kv.x, dot[0][j]);
                dot[0][j] = fmaf(xr[1].x, kv.y, dot[0][j]);
                dot[0][j] = fmaf(xr[2].x, kv.z, dot[0][j]);
                dot[0][j] = fmaf(xr[3].x, kv.w, dot[0][j]);
                dot[1][j] = fmaf(xr[0].y, kv.x, dot[1][j]);
                dot[1][j] = fmaf(xr[1].y, kv.y, dot[1][j]);
                dot[1][j] = fmaf(xr[2].y, kv.z, dot[1][j]);
                dot[1][j] = fmaf(xr[3].y, kv.w, dot[1][j]);
                dot[2][j] = fmaf(xr[0].z, kv.x, dot[2][j]);
                dot[2][j] = fmaf(xr[1].z, kv.y, dot[2][j]);
                dot[2][j] = fmaf(xr[2].z, kv.z, dot[2][j]);
                dot[2][j] = fmaf(xr[3].z, kv.w, dot[2][j]);
                dot[3][j] = fmaf(xr[0].w, kv.x, dot[3][j]);
                dot[3][j] = fmaf(xr[1].w, kv.y, dot[3][j]);
                dot[3][j] = fmaf(xr[2].w, kv.z, dot[3][j]);
                dot[3][j] = fmaf(xr[3].w, kv.w, dot[3][j]);
            }
        }

        #pragma unroll
        for (int j = 0; j < 8; ++j) {
            const int b = b0 + tb * 8 + j;
            const float kn = kns[tb * 8 + j];
            #pragma unroll
            for (int i = 0; i < 4; ++i) {
                float s = kn - 2.f * dot[i][j];
                if (s < bestv[i] || (s == bestv[i] && b < bestb[i])) {
                    best2v[i] = bestv[i];
                    bestv[i] = s; bestb[i] = b;
                } else {
                    best2v[i] = fminf(best2v[i], s);
                }
            }
        }
    }

    // merge across the 16 threads (tb) sharing each row group, track 2nd-best
    #pragma unroll
    for (int off = 8; off >= 1; off >>= 1) {
        #pragma unroll
        for (int i = 0; i < 4; ++i) {
            float ov = __shfl_xor(bestv[i], off, 64);
            int   ob = __shfl_xor(bestb[i], off, 64);
            float os = __shfl_xor(best2v[i], off, 64);
            float nb2 = fminf(fminf(best2v[i], os), fmaxf(bestv[i], ov));
            if (ov < bestv[i] || (ov == bestv[i] && ob < bestb[i])) {
                bestv[i] = ov; bestb[i] = ob;
            }
            best2v[i] = nb2;
        }
    }
    if (tb == 0) {
        #pragma unroll
        for (int i = 0; i < 4; ++i) {
            sbest[tr * 4 + i]  = bestb[i];
            sbestv[tr * 4 + i] = bestv[i];
            if ((best2v[i] - bestv[i]) < TAU) {
                int idx = atomicAdd(count, 1);
                if (idx < LISTCAP) flaglist[idx] = r0 + tr * 4 + i;
            }
        }
    }
    __syncthreads();

    if (tid < 64)
        out[(size_t)r0 + tid] = (float)sbest[tid];

    // stats: quad (4 threads) per row, 16 dims each; d2 = ||x||^2 + bestv
    const int tt = tid >> 2;
    const int cq = tid & 3;
    const float m = mask[r0 + tt];

    float sx = 0.f, sxx = 0.f;
    #pragma unroll
    for (int ci = 0; ci < 16; ++ci) {
        int c = cq * 16 + ci;
        float xv = xs[c][tt];
        sx += xv;
        sxx = fmaf(xv, xv, sxx);
    }
    sx  += __shfl_xor(sx, 1, 64);  sx  += __shfl_xor(sx, 2, 64);
    sxx += __shfl_xor(sxx, 1, 64); sxx += __shfl_xor(sxx, 2, 64);

    float d2 = sxx + sbestv[tt];
    float vals[5] = { m * d2, d2, m, sx, sxx };
    if (cq != 0) {
        #pragma unroll
        for (int q = 0; q < 5; ++q) vals[q] = 0.f;
    }
    #pragma unroll
    for (int off = 4; off <= 32; off <<= 1) {
        #pragma unroll
        for (int q = 0; q < 5; ++q) vals[q] += __shfl_xor(vals[q], off, 64);
    }
    const int wid = tid >> 6, lane = tid & 63;
    if (lane == 0) {
        #pragma unroll
        for (int q = 0; q < 5; ++q) sacc[wid][q] = vals[q];
    }
    __syncthreads();
    if (tid == 0) {
        #pragma unroll
        for (int q = 0; q < 5; ++q)
            partials[(size_t)blockIdx.x * 8 + q] =
                sacc[0][q] + sacc[1][q] + sacc[2][q] + sacc[3][q];
    }
}

// ------------------------------------------------------------------ fixup ----
// np-f32-exact recompute of flagged rows:
//   dist = fl32( fl32(xx - fl32(2*dot)) + kk ), dot = sequential fmaf over c,
//   xx/kk = numpy pairwise 8-acc sums of rounded squares. First-occurrence min.
__global__ __launch_bounds__(256) void fixup_kernel(const float* __restrict__ x,
                                                    const float* __restrict__ k,
                                                    float* __restrict__ out) {
    __shared__ float xv[C_DIM];
    __shared__ float sxx;
    __shared__ float redv[4];
    __shared__ int   redb[4];
    const int tid = threadIdx.x;
    const int* count    = (const int*)(out + NT) + SCR_COUNT;
    const int* flaglist = (const int*)(out + NT) + SCR_LIST;
    int cnt = *count;
    if (cnt > LISTCAP) cnt = LISTCAP;

    for (int it = blockIdx.x; it < cnt; it += gridDim.x) {
        const int row = flaglist[it];
        const int n = row >> 13, t = row & (T_DIM - 1);
        if (tid < C_DIM)
            xv[tid] = x[((size_t)n * C_DIM + tid) * T_DIM + t];
        __syncthreads();
        if (tid == 0) sxx = np_sumsq64(xv);
        __syncthreads();
        const float xx = sxx;

        float bv = __builtin_inff();
        int   bb = 0x7fffffff;
        for (int b = tid; b < KB; b += 256) {       // ascending per thread
            const float* kr = k + (size_t)b * C_DIM;
            float dot = 0.f;
            #pragma unroll
            for (int c = 0; c < C_DIM; ++c)
                dot = fmaf(xv[c], kr[c], dot);
            float kk = np_sumsq64(kr);
            float d  = __fadd_rn(__fsub_rn(xx, __fadd_rn(dot, dot)), kk);
            if (d < bv) { bv = d; bb = b; }
        }
        #pragma unroll
        for (int off = 1; off <= 32; off <<= 1) {
            float ov = __shfl_xor(bv, off, 64);
            int   ob = __shfl_xor(bb, off, 64);
            if (ov < bv || (ov == bv && ob < bb)) { bv = ov; bb = ob; }
        }
        const int wid = tid >> 6, lane = tid & 63;
        if (lane == 0) { redv[wid] = bv; redb[wid] = bb; }
        __syncthreads();
        if (tid == 0) {
            float fv = redv[0]; int fb = redb[0];
            #pragma unroll
            for (int w = 1; w < 4; ++w) {
                if (redv[w] < fv || (redv[w] == fv && redb[w] < fb)) {
                    fv = redv[w]; fb = redb[w];
                }
            }
            out[row] = (float)fb;
        }
        __syncthreads();
    }
}

// ------------------------------------------------------------- finalize ----
__global__ __launch_bounds__(256) void finalize_kernel(float* __restrict__ out) {
    const float* partials = (out + NT) + SCR_PART;
    const int tid = threadIdx.x;
    double vals[5] = {0, 0, 0, 0, 0};
    for (int i = tid; i < NBLK; i += 256)
        #pragma unroll
        for (int q = 0; q < 5; ++q) vals[q] += (double)partials[(size_t)i * 8 + q];
    #pragma unroll
    for (int off = 1; off <= 32; off <<= 1)
        #pragma unroll
        for (int q = 0; q < 5; ++q) vals[q] += __shfl_xor(vals[q], off, 64);
    __shared__ double sred[4][5];
    const int wid = tid >> 6, lane = tid & 63;
    if (lane == 0)
        for (int q = 0; q < 5; ++q) sred[wid][q] = vals[q];
    __syncthreads();
    if (tid == 0) {
        double cm  = sred[0][0] + sred[1][0] + sred[2][0] + sred[3][0];
        double fs  = sred[0][1] + sred[1][1] + sred[2][1] + sred[3][1];
        double ms  = sred[0][2] + sred[1][2] + sred[2][2] + sred[3][2];
        double sx  = sred[0][3] + sred[1][3] + sred[2][3] + sred[3][3];
        double sxx = sred[0][4] + sred[1][4] + sred[2][4] + sred[3][4];
        double sz  = (double)TOTX;
        out[NT + TOTX + 0] = (float)(cm / (ms * (double)C_DIM));
        out[NT + TOTX + 1] = (float)(fs / (double)NT);
        out[NT + TOTX + 2] = (float)sqrt(fmax(0.0, (sxx - sx * sx / sz) / sz));
    }
}

// --------------------------------------------------------------------- x_d ----
// Runs LAST: overwrites the scratch region with real x_d values.
__global__ __launch_bounds__(256) void xd_kernel(const float* __restrict__ mask,
                                                 const float* __restrict__ k,
                                                 float* __restrict__ out) {
    const int row = blockIdx.x * 256 + threadIdx.x;
    const int n = row >> 13, t = row & (T_DIM - 1);
    const int b = (int)out[row];
    const float m = mask[row];
    const float* kr = k + (size_t)b * C_DIM;
    float* xd = out + NT;
    #pragma unroll
    for (int c = 0; c < C_DIM; ++c)
        xd[((size_t)n * C_DIM + c) * T_DIM + t] = kr[c] * m;
}

// ----------------------------------------------------------------- launch ----
extern "C" void kernel_launch(void* const* d_in, const int* in_sizes, int n_in,
                              void* d_out, int out_size, void* d_ws, size_t ws_size,
                              hipStream_t stream) {
    (void)in_sizes; (void)n_in; (void)out_size; (void)d_ws; (void)ws_size;
    const float* x    = (const float*)d_in[0];
    const float* mask = (const float*)d_in[1];
    const float* k    = (const float*)d_in[2];
    float* out = (float*)d_out;

    init_kernel<<<1, 64, 0, stream>>>(out);
    argmin_kernel<<<NBLK, 256, 0, stream>>>(x, mask, k, out);
    fixup_kernel<<<64, 256, 0, stream>>>(x, k, out);
    finalize_kernel<<<1, 256, 0, stream>>>(out);
    xd_kernel<<<NT / 256, 256, 0, stream>>>(mask, k, out);
}

// Round 7
// 125.649 us; speedup vs baseline: 3.0472x; 3.0472x over previous
//
#include <hip/hip_runtime.h>

#define T_DIM 8192
#define N_DIM 8
#define C_DIM 64
#define KB    2048
#define NT    (N_DIM * T_DIM)        // 65536 rows
#define TOTX  ((size_t)NT * C_DIM)   // 4194304 elements
#define ROWS_BLK 128
#define NBLK  (NT / ROWS_BLK)        // 512 blocks
#define LISTCAP 8192
#define TAU   5e-4f

// Scratch lives inside out's x_d region (out + NT), overwritten LAST by
// xd_kernel. Offsets in FLOAT units from out+NT:
#define SCR_COUNT 0                   // int
#define SCR_LIST  16                  // int[8192]   -> ends 8208
#define SCR_PART  8448                // float[512][8] -> ends 12544
#define SCR_KNS   16384               // float[2048]  -> ends 18432
#define SCR_KHI   32768               // f16[2048*64] = 65536 floats -> ends 98304
#define SCR_KLO   98304               // f16[2048*64] -> ends 163840  (< 4194304)

typedef _Float16 half_t;
typedef _Float16 f16x8 __attribute__((ext_vector_type(8)));
typedef float    f32x16 __attribute__((ext_vector_type(16)));

// numpy pairwise sum (n=64) of squares for the np-exact fixup.
__device__ __forceinline__ float np_sumsq64(const float* __restrict__ a) {
    float r[8];
    #pragma unroll
    for (int j = 0; j < 8; ++j) r[j] = __fmul_rn(a[j], a[j]);
    #pragma unroll
    for (int i = 8; i < 64; i += 8)
        #pragma unroll
        for (int j = 0; j < 8; ++j)
            r[j] = __fadd_rn(r[j], __fmul_rn(a[i + j], a[i + j]));
    return __fadd_rn(__fadd_rn(__fadd_rn(r[0], r[1]), __fadd_rn(r[2], r[3])),
                     __fadd_rn(__fadd_rn(r[4], r[5]), __fadd_rn(r[6], r[7])));
}

// ------------------------------------------------------------------ k prep ----
// Split k into f16 hi/lo (lo scaled by 2048), PRE-SWIZZLED slot order so the
// argmin kernel's linear LDS staging yields the swizzled layout. Also ||k||^2.
__global__ __launch_bounds__(256) void kprep_kernel(const float* __restrict__ k,
                                                    float* __restrict__ out) {
    float* base = out + NT;
    const int bin = blockIdx.x * 256 + threadIdx.x;   // grid 8 -> 2048
    if (blockIdx.x == 0 && threadIdx.x == 0) ((int*)base)[SCR_COUNT] = 0;

    float kv[64];
    #pragma unroll
    for (int i = 0; i < 16; ++i)
        *(float4*)&kv[i * 4] = *(const float4*)(k + (size_t)bin * 64 + i * 4);

    float kn = 0.f;
    #pragma unroll
    for (int c = 0; c < 64; ++c) kn = fmaf(kv[c], kv[c], kn);
    base[SCR_KNS + bin] = kn;

    half_t* khi = (half_t*)(base + SCR_KHI);
    half_t* klo = (half_t*)(base + SCR_KLO);
    #pragma unroll
    for (int slot = 0; slot < 8; ++slot) {
        f16x8 h8, l8;
        #pragma unroll
        for (int e = 0; e < 8; ++e) {
            float xv = kv[slot * 8 + e];
            half_t hh = (half_t)xv;
            h8[e] = hh;
            l8[e] = (half_t)((xv - (float)hh) * 2048.f);
        }
        const int pos = slot ^ (bin & 7);
        *(f16x8*)(khi + (size_t)bin * 64 + pos * 8) = h8;
        *(f16x8*)(klo + (size_t)bin * 64 + pos * 8) = l8;
    }
}

// ------------------------------------------------------------------ argmin ----
// Block: 256 threads (4 waves), 128 rows. Each wave: 32 rows x 2048 bins via
// mfma_f32_32x32x16_f16, 3-pass f16 split. Tracks best/second-best/argmin.
__global__ __launch_bounds__(256, 2) void argmin_kernel(const float* __restrict__ x,
                                                        const float* __restrict__ mask,
                                                        float* __restrict__ out) {
    __shared__ char   u_buf[33792];            // xs f32[64][132]  OR  k-chunk f16
    __shared__ half_t xhi_s[128][64];
    __shared__ half_t xlo_s[128][64];
    __shared__ float  kns_s[2048];
    __shared__ float  sxrow_s[128], sxxrow_s[128];
    __shared__ float  wacc_s[4][8];

    float* base = out + NT;
    const int tid = threadIdx.x;
    const int l   = tid & 63, w = tid >> 6;
    const int r0  = blockIdx.x * ROWS_BLK;
    const int n   = r0 >> 13;
    const int t0  = r0 & (T_DIM - 1);

    // stage ||k||^2 (8 KB, once)
    #pragma unroll
    for (int i = 0; i < 8; ++i)
        kns_s[i * 256 + tid] = base[SCR_KNS + i * 256 + tid];

    // phase 1: transpose-stage x rows into xs[c][row]
    float (*xs)[132] = (float(*)[132])u_buf;
    #pragma unroll
    for (int it = 0; it < 8; ++it) {
        int idx = it * 256 + tid;     // 2048 float4s
        int c   = idx >> 5;
        int q   = idx & 31;
        float4 v = *(const float4*)(x + ((size_t)n * C_DIM + c) * T_DIM + t0 + q * 4);
        *(float4*)&xs[c][q * 4] = v;
    }
    __syncthreads();

    // phase 2: f16 hi/lo split of x into A-fragment layout (swizzled slots)
    {
        const int row = tid >> 1, h = tid & 1;
        float sx = 0.f, sxx = 0.f;
        #pragma unroll
        for (int j = 0; j < 4; ++j) {
            f16x8 h8, l8;
            #pragma unroll
            for (int e = 0; e < 8; ++e) {
                int c = h * 32 + j * 8 + e;
                float xv = xs[c][row];
                half_t hh = (half_t)xv;
                h8[e] = hh;
                l8[e] = (half_t)((xv - (float)hh) * 2048.f);
                sx += xv; sxx = fmaf(xv, xv, sxx);
            }
            const int slot = (h * 4 + j) ^ (row & 7);
            *(f16x8*)&xhi_s[row][slot * 8] = h8;
            *(f16x8*)&xlo_s[row][slot * 8] = l8;
        }
        sx += __shfl_xor(sx, 1, 64);
        sxx += __shfl_xor(sxx, 1, 64);
        if (h == 0) { sxrow_s[row] = sx; sxxrow_s[row] = sxx; }
    }
    __syncthreads();

    // A fragments (persistent): rows w*32+col, K=64 in 4 k-steps
    const int col = l & 31, kg = l >> 5;
    const int arow = w * 32 + col;
    f16x8 a_hi[4], a_lo[4];
    #pragma unroll
    for (int s = 0; s < 4; ++s) {
        const int slot = (2 * s + kg) ^ (arow & 7);
        a_hi[s] = *(const f16x8*)&xhi_s[arow][slot * 8];
        a_lo[s] = *(const f16x8*)&xlo_s[arow][slot * 8];
    }

    float bestv[16], best2v[16];
    int   bestb[16];
    #pragma unroll
    for (int r = 0; r < 16; ++r) {
        bestv[r] = __builtin_inff(); best2v[r] = __builtin_inff(); bestb[r] = 0;
    }

    half_t* khi_l = (half_t*)u_buf;            // chunk [128][64]
    half_t* klo_l = khi_l + 8192;
    const f16x8* khi_g8 = (const f16x8*)(base + SCR_KHI);
    const f16x8* klo_g8 = (const f16x8*)(base + SCR_KLO);

    for (int ch = 0; ch < 16; ++ch) {
        __syncthreads();
        #pragma unroll
        for (int it = 0; it < 4; ++it) {
            int idx = it * 256 + tid;          // 1024 f16x8 per half
            ((f16x8*)khi_l)[idx] = khi_g8[(size_t)ch * 1024 + idx];
            ((f16x8*)klo_l)[idx] = klo_g8[(size_t)ch * 1024 + idx];
        }
        __syncthreads();

        #pragma unroll
        for (int t4 = 0; t4 < 4; ++t4) {
            const int lrow = t4 * 32 + col;
            f16x8 b_hi[4], b_lo[4];
            #pragma unroll
            for (int s = 0; s < 4; ++s) {
                const int slot = (2 * s + kg) ^ (lrow & 7);
                b_hi[s] = *(const f16x8*)&khi_l[lrow * 64 + slot * 8];
                b_lo[s] = *(const f16x8*)&klo_l[lrow * 64 + slot * 8];
            }
            const float kn   = kns_s[ch * 128 + lrow];
            const int   binf = ch * 128 + lrow;

            f32x16 acc1, acc2;
            #pragma unroll
            for (int r = 0; r < 16; ++r) { acc1[r] = 0.f; acc2[r] = 0.f; }
            #pragma unroll
            for (int s = 0; s < 4; ++s) {
                acc1 = __builtin_amdgcn_mfma_f32_32x32x16_f16(a_hi[s], b_hi[s], acc1, 0, 0, 0);
                acc2 = __builtin_amdgcn_mfma_f32_32x32x16_f16(a_hi[s], b_lo[s], acc2, 0, 0, 0);
                acc2 = __builtin_amdgcn_mfma_f32_32x32x16_f16(a_lo[s], b_hi[s], acc2, 0, 0, 0);
            }

            #pragma unroll
            for (int r = 0; r < 16; ++r) {
                float sv = fmaf(acc2[r], -9.765625e-4f, fmaf(acc1[r], -2.f, kn));
                best2v[r] = fminf(best2v[r], fmaxf(sv, bestv[r]));  // 2nd-best
                if (sv < bestv[r]) { bestv[r] = sv; bestb[r] = binf; }
            }
        }
    }

    // reduce across the 32 column-lanes of each half
    #pragma unroll
    for (int off = 1; off <= 16; off <<= 1) {
        #pragma unroll
        for (int r = 0; r < 16; ++r) {
            float ov = __shfl_xor(bestv[r], off, 64);
            int   ob = __shfl_xor(bestb[r], off, 64);
            float o2 = __shfl_xor(best2v[r], off, 64);
            float mx = fmaxf(bestv[r], ov);
            best2v[r] = fminf(fminf(best2v[r], o2), mx);
            if (ov < bestv[r] || (ov == bestv[r] && ob < bestb[r])) {
                bestv[r] = ov; bestb[r] = ob;
            }
        }
    }

    // write-out (lanes col==0 of each half own 16 rows each)
    float s0 = 0.f, s1 = 0.f, s2 = 0.f, s3 = 0.f, s4 = 0.f;
    if (col == 0) {
        int* countp = (int*)base + SCR_COUNT;
        int* listp  = (int*)base + SCR_LIST;
        #pragma unroll
        for (int r = 0; r < 16; ++r) {
            const int row_loc = w * 32 + 4 * kg + (r & 3) + 8 * (r >> 2);
            const int grow = r0 + row_loc;
            out[grow] = (float)bestb[r];
            if (best2v[r] - bestv[r] < TAU) {
                int idx = atomicAdd(countp, 1);
                if (idx < LISTCAP) listp[idx] = grow;
            }
            const float m  = mask[grow];
            const float d2 = sxxrow_s[row_loc] + bestv[r];
            s0 = fmaf(m, d2, s0); s1 += d2; s2 += m;
            s3 += sxrow_s[row_loc]; s4 += sxxrow_s[row_loc];
        }
    }
    s0 += __shfl_xor(s0, 32, 64);
    s1 += __shfl_xor(s1, 32, 64);
    s2 += __shfl_xor(s2, 32, 64);
    s3 += __shfl_xor(s3, 32, 64);
    s4 += __shfl_xor(s4, 32, 64);
    if (l == 0) {
        wacc_s[w][0] = s0; wacc_s[w][1] = s1; wacc_s[w][2] = s2;
        wacc_s[w][3] = s3; wacc_s[w][4] = s4;
    }
    __syncthreads();
    if (tid == 0) {
        float* partials = base + SCR_PART;
        #pragma unroll
        for (int q = 0; q < 5; ++q)
            partials[(size_t)blockIdx.x * 8 + q] =
                wacc_s[0][q] + wacc_s[1][q] + wacc_s[2][q] + wacc_s[3][q];
    }
}

// ------------------------------------------------------------------ fixup ----
// np-f32-exact recompute of flagged near-tie rows (first-occurrence argmin).
__global__ __launch_bounds__(256) void fixup_kernel(const float* __restrict__ x,
                                                    const float* __restrict__ k,
                                                    float* __restrict__ out) {
    __shared__ float xv[C_DIM];
    __shared__ float sxxs;
    __shared__ float redv[4];
    __shared__ int   redb[4];
    const int tid = threadIdx.x;
    const int* count    = (const int*)(out + NT) + SCR_COUNT;
    const int* flaglist = (const int*)(out + NT) + SCR_LIST;
    int cnt = *count;
    if (cnt > LISTCAP) cnt = LISTCAP;

    for (int it = blockIdx.x; it < cnt; it += gridDim.x) {
        const int row = flaglist[it];
        const int n = row >> 13, t = row & (T_DIM - 1);
        if (tid < C_DIM)
            xv[tid] = x[((size_t)n * C_DIM + tid) * T_DIM + t];
        __syncthreads();
        if (tid == 0) sxxs = np_sumsq64(xv);
        __syncthreads();
        const float xx = sxxs;

        float bv = __builtin_inff();
        int   bb = 0x7fffffff;
        for (int b = tid; b < KB; b += 256) {
            const float* kr = k + (size_t)b * C_DIM;
            float dot = 0.f;
            #pragma unroll
            for (int c = 0; c < C_DIM; ++c)
                dot = fmaf(xv[c], kr[c], dot);
            float kk = np_sumsq64(kr);
            float d  = __fadd_rn(__fsub_rn(xx, __fadd_rn(dot, dot)), kk);
            if (d < bv) { bv = d; bb = b; }
        }
        #pragma unroll
        for (int off = 1; off <= 32; off <<= 1) {
            float ov = __shfl_xor(bv, off, 64);
            int   ob = __shfl_xor(bb, off, 64);
            if (ov < bv || (ov == bv && ob < bb)) { bv = ov; bb = ob; }
        }
        const int wid = tid >> 6, lane = tid & 63;
        if (lane == 0) { redv[wid] = bv; redb[wid] = bb; }
        __syncthreads();
        if (tid == 0) {
            float fv = redv[0]; int fb = redb[0];
            #pragma unroll
            for (int wq = 1; wq < 4; ++wq) {
                if (redv[wq] < fv || (redv[wq] == fv && redb[wq] < fb)) {
                    fv = redv[wq]; fb = redb[wq];
                }
            }
            out[row] = (float)fb;
        }
        __syncthreads();
    }
}

// ------------------------------------------------------------- finalize ----
__global__ __launch_bounds__(256) void finalize_kernel(float* __restrict__ out) {
    const float* partials = (out + NT) + SCR_PART;
    const int tid = threadIdx.x;
    double vals[5] = {0, 0, 0, 0, 0};
    for (int i = tid; i < NBLK; i += 256)
        #pragma unroll
        for (int q = 0; q < 5; ++q) vals[q] += (double)partials[(size_t)i * 8 + q];
    #pragma unroll
    for (int off = 1; off <= 32; off <<= 1)
        #pragma unroll
        for (int q = 0; q < 5; ++q) vals[q] += __shfl_xor(vals[q], off, 64);
    __shared__ double sred[4][5];
    const int wid = tid >> 6, lane = tid & 63;
    if (lane == 0)
        for (int q = 0; q < 5; ++q) sred[wid][q] = vals[q];
    __syncthreads();
    if (tid == 0) {
        double cm  = sred[0][0] + sred[1][0] + sred[2][0] + sred[3][0];
        double fs  = sred[0][1] + sred[1][1] + sred[2][1] + sred[3][1];
        double ms  = sred[0][2] + sred[1][2] + sred[2][2] + sred[3][2];
        double sx  = sred[0][3] + sred[1][3] + sred[2][3] + sred[3][3];
        double sxx = sred[0][4] + sred[1][4] + sred[2][4] + sred[3][4];
        double sz  = (double)TOTX;
        out[NT + TOTX + 0] = (float)(cm / (ms * (double)C_DIM));
        out[NT + TOTX + 1] = (float)(fs / (double)NT);
        out[NT + TOTX + 2] = (float)sqrt(fmax(0.0, (sxx - sx * sx / sz) / sz));
    }
}

// --------------------------------------------------------------------- x_d ----
// Runs LAST: overwrites the scratch region with real x_d values.
__global__ __launch_bounds__(256) void xd_kernel(const float* __restrict__ mask,
                                                 const float* __restrict__ k,
                                                 float* __restrict__ out) {
    const int row = blockIdx.x * 256 + threadIdx.x;
    const int n = row >> 13, t = row & (T_DIM - 1);
    const int b = (int)out[row];
    const float m = mask[row];
    const float* kr = k + (size_t)b * C_DIM;
    float* xd = out + NT;
    #pragma unroll
    for (int c = 0; c < C_DIM; ++c)
        xd[((size_t)n * C_DIM + c) * T_DIM + t] = kr[c] * m;
}

// ----------------------------------------------------------------- launch ----
extern "C" void kernel_launch(void* const* d_in, const int* in_sizes, int n_in,
                              void* d_out, int out_size, void* d_ws, size_t ws_size,
                              hipStream_t stream) {
    (void)in_sizes; (void)n_in; (void)out_size; (void)d_ws; (void)ws_size;
    const float* x    = (const float*)d_in[0];
    const float* mask = (const float*)d_in[1];
    const float* k    = (const float*)d_in[2];
    float* out = (float*)d_out;

    kprep_kernel<<<KB / 256, 256, 0, stream>>>(k, out);
    argmin_kernel<<<NBLK, 256, 0, stream>>>(x, mask, out);
    fixup_kernel<<<64, 256, 0, stream>>>(x, k, out);
    finalize_kernel<<<1, 256, 0, stream>>>(out);
    xd_kernel<<<NT / 256, 256, 0, stream>>>(mask, k, out);
}